// Round 5
// baseline (107.657 us; speedup 1.0000x reference)
//
#include <hip/hip_runtime.h>

// channel_attention: the attention branch is the identity (softmax over m
// sums to 1 in einsum 'bdct,bdcm->bdct'). Output = LN_c(pW @ x + pb) per
// (b,d,t) column.
//
// R4: persistent pipelined waves. Each wave owns 4 t-tiles (strip-mined),
// W frags loaded ONCE per wave, and tile i+1's 32 x-loads are issued
// (and packed to bf16, 16 VGPR buffer) while tile i computes -> the load
// queue stays full instead of burst-stall-burst. Latency-bound fix.

#define CC    64
#define TT    3000
#define BTILE 128    // t per block per tile (4 waves x 32 cols)
#define S     6      // strips per bd -> grid 256*6 = 1536 blocks
#define TPS   4      // tiles per strip (24 total tiles / S)

typedef __attribute__((ext_vector_type(8)))  short short8;
typedef __attribute__((ext_vector_type(16))) float f32x16;

static __device__ __forceinline__ short f2bf(float f) {
    unsigned u = __builtin_bit_cast(unsigned, f);
    unsigned r = (u + 0x7FFFu + ((u >> 16) & 1u)) >> 16;
    return (short)r;
}

// ws layout: Wf = 4096 shorts (8 KB); Pf = 192 floats at +8192 B.
// Wf[((ct*4+kc)*64 + lane)*8 + e] = bf16(pW[co*CC + c]),
//   co = ct*32 + (lane&31), c = kc*16 + (lane>>5)*8 + e.
// Pf[a*64 + (ct*2+half)*16 + r] = {pb,pg,pbeta}[ct*32 + half*4 + (r&3) + 8*(r>>2)]
__global__ void pack_params(const float* __restrict__ pW,
                            const float* __restrict__ pb,
                            const float* __restrict__ pg,
                            const float* __restrict__ pbeta,
                            short* __restrict__ Wf, float* __restrict__ Pf)
{
    int i = blockIdx.x * 256 + threadIdx.x;
    if (i < 4096) {
        int e = i & 7, l = (i >> 3) & 63, f = i >> 9;
        int ct = f >> 2, kc = f & 3;
        int co = ct * 32 + (l & 31);
        int c  = kc * 16 + (l >> 5) * 8 + e;
        Wf[i] = f2bf(pW[co * CC + c]);
    } else if (i < 4096 + 192) {
        int j = i - 4096;
        int a = j >> 6, q = j & 63;
        int r = q & 15, half = (q >> 4) & 1, ct = q >> 5;
        int co = ct * 32 + half * 4 + (r & 3) + 8 * (r >> 2);
        const float* src = (a == 0) ? pb : (a == 1) ? pg : pbeta;
        Pf[j] = src[co];
    }
}

// Load+convert tile ti's x-column slice into packed bf16 frags BB[4].
#define LOADT(BB, ti) do {                                                  \
    const int t_  = ((s + S * (ti)) * BTILE) + wid * 32 + col;              \
    const int tc_ = (t_ < TT) ? t_ : (TT - 1);                              \
    const float* __restrict__ xp_ = xbd + tc_;                              \
    _Pragma("unroll")                                                       \
    for (int kc_ = 0; kc_ < 4; ++kc_) {                                     \
        _Pragma("unroll")                                                   \
        for (int e_ = 0; e_ < 8; ++e_)                                      \
            BB[kc_][e_] = f2bf(xp_[(size_t)(kc_ * 16 + half * 8 + e_) * TT]); \
    }                                                                       \
} while (0)

// MFMA + bias + LN + store for tile ti from packed frags BB[4].
#define COMPUTE(BB, ti) do {                                                \
    const int t_ = ((s + S * (ti)) * BTILE) + wid * 32 + col;               \
    const bool act_ = (t_ < TT);                                            \
    f32x16 acc[2];                                                          \
    _Pragma("unroll")                                                       \
    for (int r_ = 0; r_ < 16; ++r_) { acc[0][r_] = 0.0f; acc[1][r_] = 0.0f; } \
    _Pragma("unroll")                                                       \
    for (int kc_ = 0; kc_ < 4; ++kc_) {                                     \
        acc[0] = __builtin_amdgcn_mfma_f32_32x32x16_bf16(aW[0][kc_], BB[kc_], acc[0], 0, 0, 0); \
        acc[1] = __builtin_amdgcn_mfma_f32_32x32x16_bf16(aW[1][kc_], BB[kc_], acc[1], 0, 0, 0); \
    }                                                                       \
    float s_ = 0.0f, s2_ = 0.0f;                                            \
    _Pragma("unroll")                                                       \
    for (int ct_ = 0; ct_ < 2; ++ct_) {                                     \
        const float4* pbv_ = (const float4*)(Pf + (ct_ * 2 + half) * 16);   \
        _Pragma("unroll")                                                   \
        for (int q_ = 0; q_ < 4; ++q_) {                                    \
            const float4 b4_ = pbv_[q_];                                    \
            acc[ct_][q_ * 4 + 0] += b4_.x;                                  \
            acc[ct_][q_ * 4 + 1] += b4_.y;                                  \
            acc[ct_][q_ * 4 + 2] += b4_.z;                                  \
            acc[ct_][q_ * 4 + 3] += b4_.w;                                  \
        }                                                                   \
        _Pragma("unroll")                                                   \
        for (int r_ = 0; r_ < 16; ++r_) {                                   \
            const float v_ = acc[ct_][r_];                                  \
            s_ += v_;                                                       \
            s2_ = fmaf(v_, v_, s2_);                                        \
        }                                                                   \
    }                                                                       \
    s_  += __shfl_xor(s_, 32);                                              \
    s2_ += __shfl_xor(s2_, 32);                                             \
    const float mu_   = s_ * (1.0f / CC);                                   \
    const float rstd_ = rsqrtf(s2_ * (1.0f / CC) - mu_ * mu_ + 1e-5f);      \
    if (act_) {                                                             \
        float* __restrict__ op_ = obd + t_;                                 \
        _Pragma("unroll")                                                   \
        for (int ct_ = 0; ct_ < 2; ++ct_) {                                 \
            const float4* pgv_ = (const float4*)(Pf + 64  + (ct_ * 2 + half) * 16); \
            const float4* pev_ = (const float4*)(Pf + 128 + (ct_ * 2 + half) * 16); \
            _Pragma("unroll")                                               \
            for (int q_ = 0; q_ < 4; ++q_) {                                \
                const float4 g4_ = pgv_[q_];                                \
                const float4 e4_ = pev_[q_];                                \
                const float gg_[4] = {g4_.x, g4_.y, g4_.z, g4_.w};          \
                const float ee_[4] = {e4_.x, e4_.y, e4_.z, e4_.w};          \
                _Pragma("unroll")                                           \
                for (int j_ = 0; j_ < 4; ++j_) {                            \
                    const int r_  = q_ * 4 + j_;                            \
                    const int co_ = ct_ * 32 + half * 4 + (r_ & 3) + 8 * (r_ >> 2); \
                    op_[(size_t)co_ * TT] = (acc[ct_][r_] - mu_) * rstd_ * gg_[j_] + ee_[j_]; \
                }                                                           \
            }                                                               \
        }                                                                   \
    }                                                                       \
} while (0)

__global__ __launch_bounds__(256) void fused_mfma_ln(
    const float* __restrict__ x,    // [BD, CC, TT]
    const short* __restrict__ Wf,
    const float* __restrict__ Pf,
    float* __restrict__ out)        // [BD, CC, TT]
{
    const int tid  = threadIdx.x;
    const int lane = tid & 63;
    const int wid  = tid >> 6;
    const int bd   = blockIdx.x / S;
    const int s    = blockIdx.x - bd * S;
    const int col  = lane & 31;
    const int half = lane >> 5;

    const float* __restrict__ xbd = x   + (size_t)bd * (CC * TT);
    float* __restrict__       obd = out + (size_t)bd * (CC * TT);

    // All of W, fragment-ordered, ONCE per wave: 8 x 16B loads (32 VGPR).
    short8 aW[2][4];
#pragma unroll
    for (int ct = 0; ct < 2; ++ct)
#pragma unroll
        for (int kc = 0; kc < 4; ++kc)
            aW[ct][kc] = ((const short8*)Wf)[(ct * 4 + kc) * 64 + lane];

    // Software pipeline over TPS=4 tiles: load i+1 while computing i.
    short8 bbA[4], bbB[4];
    LOADT(bbA, 0);
    LOADT(bbB, 1); COMPUTE(bbA, 0);
    LOADT(bbA, 2); COMPUTE(bbB, 1);
    LOADT(bbB, 3); COMPUTE(bbA, 2);
    COMPUTE(bbB, 3);
}

extern "C" void kernel_launch(void* const* d_in, const int* in_sizes, int n_in,
                              void* d_out, int out_size, void* d_ws, size_t ws_size,
                              hipStream_t stream) {
    // setup_inputs order: x, qW, qb, qg, qbeta, kW, kb, kg, kbeta, pW, pb, pg, pbeta
    const float* x     = (const float*)d_in[0];
    const float* pW    = (const float*)d_in[9];
    const float* pb    = (const float*)d_in[10];
    const float* pg    = (const float*)d_in[11];
    const float* pbeta = (const float*)d_in[12];
    float* out = (float*)d_out;

    short* Wf = (short*)d_ws;                          // 8 KB
    float* Pf = (float*)((char*)d_ws + 8192);          // 768 B

    pack_params<<<17, 256, 0, stream>>>(pW, pb, pg, pbeta, Wf, Pf);

    const int BD = 32 * 8;
    dim3 grid(BD * S);      // 1536 blocks
    dim3 block(256);
    fused_mfma_ln<<<grid, block, 0, stream>>>(x, Wf, Pf, out);
}

// Round 6
// 93.846 us; speedup vs baseline: 1.1472x; 1.1472x over previous
//
#include <hip/hip_runtime.h>

// channel_attention: the attention branch is the identity (softmax over m
// sums to 1 in einsum 'bdct,bdcm->bdct'). Output = LN_c(pW @ x + pb) per
// (b,d,t) column.
//
// R5: segment-size fix. All prior rounds plateaued at ~2.7 TB/s with scalar
// dword VMEM (128B segments @ 12kB stride) regardless of occupancy/engine.
// This version stages x[64][128] f32 in LDS via float4 (512B/row segments),
// feeds MFMA B-frags with conflict-free ds_read_b32, writes LN results back
// into the SAME LDS buffer (per-wave column-disjoint -> 2 barriers only),
// then stores via float4 (512B/row segments). T1 XCD-chunked block swizzle.

#define CC      64
#define TT      3000
#define TILE_T  128
#define NTB     24            // ceil(TT / TILE_T)
#define NWG     (256 * NTB)   // 6144 blocks, % 8 == 0 -> bijective swizzle
#define CPX     (NWG / 8)     // 768

typedef __attribute__((ext_vector_type(8)))  short short8;
typedef __attribute__((ext_vector_type(16))) float f32x16;

static __device__ __forceinline__ unsigned f2bf(float f) {
    // round-to-nearest-even f32 -> bf16 (inputs finite)
    unsigned u = __builtin_bit_cast(unsigned, f);
    return (u + 0x7FFFu + ((u >> 16) & 1u)) >> 16;
}

// ws layout: Wf = 4096 shorts (8 KB); Pf = 192 floats at +8192 B.
// Wf[((ct*4+kc)*64 + lane)*8 + e] = bf16(pW[co*CC + c]),
//   co = ct*32 + (lane&31), c = kc*16 + (lane>>5)*8 + e.
// Pf[a*64 + (ct*2+half)*16 + r] = {pb,pg,pbeta}[ct*32 + half*4 + (r&3) + 8*(r>>2)]
__global__ void pack_params(const float* __restrict__ pW,
                            const float* __restrict__ pb,
                            const float* __restrict__ pg,
                            const float* __restrict__ pbeta,
                            short* __restrict__ Wf, float* __restrict__ Pf)
{
    int i = blockIdx.x * 256 + threadIdx.x;
    if (i < 4096) {
        int e = i & 7, l = (i >> 3) & 63, f = i >> 9;
        int ct = f >> 2, kc = f & 3;
        int co = ct * 32 + (l & 31);
        int c  = kc * 16 + (l >> 5) * 8 + e;
        Wf[i] = (short)f2bf(pW[co * CC + c]);
    } else if (i < 4096 + 192) {
        int j = i - 4096;
        int a = j >> 6, q = j & 63;
        int r = q & 15, half = (q >> 4) & 1, ct = q >> 5;
        int co = ct * 32 + half * 4 + (r & 3) + 8 * (r >> 2);
        const float* src = (a == 0) ? pb : (a == 1) ? pg : pbeta;
        Pf[j] = src[co];
    }
}

__global__ __launch_bounds__(256, 4) void fused_mfma_ln(
    const float* __restrict__ x,    // [BD, CC, TT]
    const short* __restrict__ Wf,
    const float* __restrict__ Pf,
    float* __restrict__ out)        // [BD, CC, TT]
{
    __shared__ float xy[CC * TILE_T];   // 32 KB, [c][t] f32; reused for y

    const int bid = blockIdx.x;
    const int swz = (bid & 7) * CPX + (bid >> 3);   // XCD-chunked, bijective
    const int bd  = swz / NTB;
    const int tb  = swz - bd * NTB;
    const int t0b = tb * TILE_T;

    const int tid  = threadIdx.x;
    const int lane = tid & 63;
    const int wid  = tid >> 6;
    const int col  = lane & 31;
    const int half = lane >> 5;

    const size_t xbase = (size_t)bd * (CC * TT);

    // W fragments: 8 x 16B loads, issued first to overlap with staging.
    short8 aW[2][4];
#pragma unroll
    for (int ct = 0; ct < 2; ++ct)
#pragma unroll
        for (int kc = 0; kc < 4; ++kc)
            aW[ct][kc] = ((const short8*)Wf)[(ct * 4 + kc) * 64 + lane];

    // ---- Phase 1: stage x[64][128] f32 -> LDS via float4 (512B/row segs).
    // round r: lanes 0-31 cover row c (full 128-t span), lanes 32-63 row c+1.
    int tq = t0b + col * 4;
    if (tq > TT - 4) tq = TT - 4;       // tail clamp (dup data, never stored)
    float4 tmp[8];
#pragma unroll
    for (int r = 0; r < 8; ++r) {
        const int c = r * 8 + wid * 2 + half;
        tmp[r] = *(const float4*)(x + xbase + (size_t)c * TT + tq);
    }
#pragma unroll
    for (int r = 0; r < 8; ++r) {
        const int c = r * 8 + wid * 2 + half;
        *(float4*)&xy[c * TILE_T + col * 4] = tmp[r];   // b128, conflict-free
    }
    __syncthreads();

    // ---- Phase 2: B-frags from LDS (b32 reads, lanes stride 4B: free),
    // pack to bf16. Same (kc, half, e)->c rule as aW -> permutation cancels.
    const int tcol = wid * 32 + col;    // this wave's 32 columns
    short8 bx[4];
#pragma unroll
    for (int kc = 0; kc < 4; ++kc) {
        union { unsigned u[4]; short8 s; } cvt;
#pragma unroll
        for (int p = 0; p < 4; ++p) {
            const float a = xy[(kc * 16 + half * 8 + 2 * p)     * TILE_T + tcol];
            const float b = xy[(kc * 16 + half * 8 + 2 * p + 1) * TILE_T + tcol];
            cvt.u[p] = f2bf(a) | (f2bf(b) << 16);
        }
        bx[kc] = cvt.s;
    }

    f32x16 acc[2];
#pragma unroll
    for (int r = 0; r < 16; ++r) { acc[0][r] = 0.0f; acc[1][r] = 0.0f; }
#pragma unroll
    for (int kc = 0; kc < 4; ++kc) {
        acc[0] = __builtin_amdgcn_mfma_f32_32x32x16_bf16(aW[0][kc], bx[kc], acc[0], 0, 0, 0);
        acc[1] = __builtin_amdgcn_mfma_f32_32x32x16_bf16(aW[1][kc], bx[kc], acc[1], 0, 0, 0);
    }

    // ---- Phase 3: bias + LN stats (C/D layout: col=lane&31,
    // row = ct*32 + half*4 + (r&3) + 8*(r>>2)); shfl_xor(32) joins halves.
    float s = 0.0f, s2 = 0.0f;
#pragma unroll
    for (int ct = 0; ct < 2; ++ct) {
        const float4* pbv = (const float4*)(Pf + (ct * 2 + half) * 16);
#pragma unroll
        for (int q = 0; q < 4; ++q) {
            const float4 b4 = pbv[q];
            acc[ct][q * 4 + 0] += b4.x;
            acc[ct][q * 4 + 1] += b4.y;
            acc[ct][q * 4 + 2] += b4.z;
            acc[ct][q * 4 + 3] += b4.w;
        }
#pragma unroll
        for (int r = 0; r < 16; ++r) {
            const float v = acc[ct][r];
            s += v;
            s2 = fmaf(v, v, s2);
        }
    }
    s  += __shfl_xor(s, 32);
    s2 += __shfl_xor(s2, 32);
    const float mu   = s * (1.0f / CC);
    const float rstd = rsqrtf(s2 * (1.0f / CC) - mu * mu + 1e-5f);

    // ---- Phase 4: write final outputs back into the SAME LDS buffer.
    // Wave w touches only its own 32 columns -> safe aliasing, no barrier
    // needed before this (in-wave DS ordering), one barrier after.
#pragma unroll
    for (int ct = 0; ct < 2; ++ct) {
        const float4* pgv = (const float4*)(Pf + 64  + (ct * 2 + half) * 16);
        const float4* pev = (const float4*)(Pf + 128 + (ct * 2 + half) * 16);
#pragma unroll
        for (int q = 0; q < 4; ++q) {
            const float4 g4 = pgv[q];
            const float4 e4 = pev[q];
            const float gg[4] = {g4.x, g4.y, g4.z, g4.w};
            const float ee[4] = {e4.x, e4.y, e4.z, e4.w};
#pragma unroll
            for (int j = 0; j < 4; ++j) {
                const int r  = q * 4 + j;
                const int co = ct * 32 + half * 4 + (r & 3) + 8 * (r >> 2);
                xy[co * TILE_T + tcol] = (acc[ct][r] - mu) * rstd * gg[j] + ee[j];
            }
        }
    }
    __syncthreads();

    // ---- Phase 5: vectorized stores, mirror of phase 1 (512B/row segs).
    const bool stok = (t0b + col * 4) < TT;   // quad-aligned (TT % 4 == 0)
#pragma unroll
    for (int r = 0; r < 8; ++r) {
        const int c = r * 8 + wid * 2 + half;
        const float4 v = *(const float4*)&xy[c * TILE_T + col * 4];
        if (stok)
            *(float4*)(out + xbase + (size_t)c * TT + t0b + col * 4) = v;
    }
}

extern "C" void kernel_launch(void* const* d_in, const int* in_sizes, int n_in,
                              void* d_out, int out_size, void* d_ws, size_t ws_size,
                              hipStream_t stream) {
    // setup_inputs order: x, qW, qb, qg, qbeta, kW, kb, kg, kbeta, pW, pb, pg, pbeta
    const float* x     = (const float*)d_in[0];
    const float* pW    = (const float*)d_in[9];
    const float* pb    = (const float*)d_in[10];
    const float* pg    = (const float*)d_in[11];
    const float* pbeta = (const float*)d_in[12];
    float* out = (float*)d_out;

    short* Wf = (short*)d_ws;                          // 8 KB
    float* Pf = (float*)((char*)d_ws + 8192);          // 768 B

    pack_params<<<17, 256, 0, stream>>>(pW, pb, pg, pbeta, Wf, Pf);

    dim3 grid(NWG);         // 6144 blocks
    dim3 block(256);
    fused_mfma_ln<<<grid, block, 0, stream>>>(x, Wf, Pf, out);
}